// Round 6
// baseline (333.040 us; speedup 1.0000x reference)
//
#include <hip/hip_runtime.h>
#include <hip/hip_bf16.h>
#include <math.h>

#define N_HALF 2048
#define M_TOT  4096
#define D_DIM  256
#define K2     512
#define NBLK   16            // M_TOT / 256 column blocks
#define NKT    8             // K2 / 64 k-tiles
#define TILE_BYTES 32768     // 256 rows * 64 k * 2 B
#define NBLOCKS 256u

typedef __attribute__((ext_vector_type(8))) short bf16x8;
typedef __attribute__((ext_vector_type(4))) float f32x4;

static __device__ __forceinline__ unsigned short f2bf(float x) {
    union { __hip_bfloat16 h; unsigned short u; } cv;
    cv.h = __float2bfloat16(x);
    return cv.u;
}

static __device__ __forceinline__ void gll16(const void* g, void* l) {
    __builtin_amdgcn_global_load_lds(
        (const __attribute__((address_space(1))) unsigned int*)g,
        (__attribute__((address_space(3))) unsigned int*)l, 16, 0, 0);
}

// Device-scope grid barrier (Guideline 16): every thread releases its own
// stores, block syncs, lane0 does device-scope release-add then acquire-spins.
// Counter is zeroed by a hipMemsetAsync node before each kernel launch.
static __device__ __forceinline__ void gbar(unsigned* cnt, unsigned target) {
    __threadfence();
    __syncthreads();
    if (threadIdx.x == 0) {
        __hip_atomic_fetch_add(cnt, 1u, __ATOMIC_RELEASE, __HIP_MEMORY_SCOPE_AGENT);
        while (__hip_atomic_load(cnt, __ATOMIC_ACQUIRE, __HIP_MEMORY_SCOPE_AGENT) < target) {}
    }
    __syncthreads();
    __threadfence();
}

// ---------------------------------------------------------------------------
// Megakernel: 256 blocks x 512 threads, 1 block/CU (128 KB LDS), 4 phases
// separated by grid barriers.
//  P1 prep: 16 rows/block -> bf16 operand tiles (pre-swizzled) + slv/cvec
//  P2 gemm: 256x256 MFMA tile, BK=64 double-buffered counted-vmcnt pipeline,
//           fused LSE epilogue -> (m,s) partials + pos[i] = sim[i, i^2048]
//  P3 finalize: per-row combine 16 partials -> loss[i] = lse - pos[i]
//  P4 mean: block 0 reduces 4096 losses -> out[0]
// ---------------------------------------------------------------------------
__global__ __launch_bounds__(512, 2) void mega_kernel(
        const float* __restrict__ loc1, const float* __restrict__ scale1,
        const float* __restrict__ loc2, const float* __restrict__ scale2,
        unsigned short* __restrict__ Ab, unsigned short* __restrict__ Bb,
        float* __restrict__ slv, float* __restrict__ cvec,
        float* __restrict__ pm, float* __restrict__ ps,
        float* __restrict__ pos, float* __restrict__ loss,
        float* __restrict__ out, unsigned* __restrict__ cnt) {
    extern __shared__ __align__(16) char smem[];   // 131072 B
    const int t = threadIdx.x;
    const int lane = t & 63, wid = t >> 6;
    const int b = blockIdx.x;

    // ================= Phase 1: prep (16 rows per block) =================
    {
        #pragma unroll
        for (int rep = 0; rep < 2; ++rep) {
            const int i = b * 16 + wid * 2 + rep;
            const float* mup = (i < N_HALF) ? loc1 + (size_t)i * D_DIM   : loc2 + (size_t)(i - N_HALF) * D_DIM;
            const float* vap = (i < N_HALF) ? scale1 + (size_t)i * D_DIM : scale2 + (size_t)(i - N_HALF) * D_DIM;
            const float4 mu = *(const float4*)(mup + lane * 4);
            const float4 va = *(const float4*)(vap + lane * 4);
            const float4 iv = {1.0f / va.x, 1.0f / va.y, 1.0f / va.z, 1.0f / va.w};

            float lacc = __logf(va.x * va.y * va.z * va.w);
            float cacc = mu.x * mu.x * iv.x + mu.y * mu.y * iv.y
                       + mu.z * mu.z * iv.z + mu.w * mu.w * iv.w;
            #pragma unroll
            for (int off = 1; off < 64; off <<= 1) {
                lacc += __shfl_xor(lacc, off, 64);
                cacc += __shfl_xor(cacc, off, 64);
            }
            if (lane == 0) { slv[i] = lacc; cvec[i] = cacc; }

            const int by = i >> 8, r = i & 255;
            const int rsw = r & 7;
            char* const abase = (char*)Ab + (size_t)by * (NKT * TILE_BYTES) + r * 128;
            char* const bbase = (char*)Bb + (size_t)by * (NKT * TILE_BYTES) + r * 128;
            #define ST4(base, k, v0, v1, v2, v3)                                            \
                {   const int kk = (k);                                                     \
                    const int kb = kk >> 6, sl = ((kk >> 3) & 7) ^ rsw, hf = (kk >> 2) & 1; \
                    ushort4 pk = {f2bf(v0), f2bf(v1), f2bf(v2), f2bf(v3)};                  \
                    *(ushort4*)((base) + (size_t)kb * TILE_BYTES + sl * 16 + hf * 8) = pk; }
            ST4(abase, lane * 4,       mu.x * mu.x + va.x, mu.y * mu.y + va.y,
                                       mu.z * mu.z + va.z, mu.w * mu.w + va.w)
            ST4(abase, 256 + lane * 4, -2.0f * mu.x, -2.0f * mu.y, -2.0f * mu.z, -2.0f * mu.w)
            ST4(bbase, lane * 4,       iv.x, iv.y, iv.z, iv.w)
            ST4(bbase, 256 + lane * 4, mu.x * iv.x, mu.y * iv.y, mu.z * iv.z, mu.w * iv.w)
            #undef ST4
        }
    }
    gbar(cnt, NBLOCKS);

    // ================= Phase 2: gemm + fused LSE =================
    {
        const int bx = b & 15, by = b >> 4;
        const int wrow = wid >> 2, wcol = wid & 3;     // 2 x 4 wave grid
        const int fr = lane & 15, g = lane >> 4;
        const int t16 = t * 16;

        int a_off[8][2], b_off[4][2];
        #pragma unroll
        for (int fm = 0; fm < 8; ++fm) {
            const int row = wrow * 128 + fm * 16 + fr;
            #pragma unroll
            for (int ks = 0; ks < 2; ++ks)
                a_off[fm][ks] = row * 128 + ((((ks * 4 + g) ^ (row & 7))) << 4);
        }
        #pragma unroll
        for (int fn = 0; fn < 4; ++fn) {
            const int row = wcol * 64 + fn * 16 + fr;
            #pragma unroll
            for (int ks = 0; ks < 2; ++ks)
                b_off[fn][ks] = 32768 + row * 128 + ((((ks * 4 + g) ^ (row & 7))) << 4);
        }

        f32x4 acc[8][4];
        #pragma unroll
        for (int i = 0; i < 8; ++i)
            #pragma unroll
            for (int j = 0; j < 4; ++j) acc[i][j] = (f32x4){0.f, 0.f, 0.f, 0.f};

        const char* gA = (const char*)Ab + (size_t)by * (NKT * TILE_BYTES);
        const char* gB = (const char*)Bb + (size_t)bx * (NKT * TILE_BYTES);

        #define STAGE(buf, kt)                                                       \
            {   const char* _tA = gA + (size_t)(kt) * TILE_BYTES;                    \
                const char* _tB = gB + (size_t)(kt) * TILE_BYTES;                    \
                char* _dA = smem + (buf) * 65536;                                    \
                char* _dB = _dA + 32768;                                             \
                gll16(_tA + t16,         _dA + t16);                                 \
                gll16(_tA + 8192 + t16,  _dA + 8192 + t16);                          \
                gll16(_tA + 16384 + t16, _dA + 16384 + t16);                         \
                gll16(_tA + 24576 + t16, _dA + 24576 + t16);                         \
                gll16(_tB + t16,         _dB + t16);                                 \
                gll16(_tB + 8192 + t16,  _dB + 8192 + t16);                          \
                gll16(_tB + 16384 + t16, _dB + 16384 + t16);                         \
                gll16(_tB + 24576 + t16, _dB + 24576 + t16); }

        STAGE(0, 0)
        STAGE(1, 1)
        asm volatile("s_waitcnt vmcnt(8)" ::: "memory");
        __builtin_amdgcn_s_barrier();
        asm volatile("" ::: "memory");

        for (int kt = 0; kt < NKT; ++kt) {
            const char* bT = smem + (kt & 1) * 65536;
            #pragma unroll
            for (int ks = 0; ks < 2; ++ks) {
                bf16x8 b0 = *(const bf16x8*)(bT + b_off[0][ks]);
                bf16x8 b1 = *(const bf16x8*)(bT + b_off[1][ks]);
                bf16x8 b2 = *(const bf16x8*)(bT + b_off[2][ks]);
                bf16x8 b3 = *(const bf16x8*)(bT + b_off[3][ks]);
                #pragma unroll
                for (int fm = 0; fm < 8; ++fm) {
                    const bf16x8 af = *(const bf16x8*)(bT + a_off[fm][ks]);
                    acc[fm][0] = __builtin_amdgcn_mfma_f32_16x16x32_bf16(af, b0, acc[fm][0], 0, 0, 0);
                    acc[fm][1] = __builtin_amdgcn_mfma_f32_16x16x32_bf16(af, b1, acc[fm][1], 0, 0, 0);
                    acc[fm][2] = __builtin_amdgcn_mfma_f32_16x16x32_bf16(af, b2, acc[fm][2], 0, 0, 0);
                    acc[fm][3] = __builtin_amdgcn_mfma_f32_16x16x32_bf16(af, b3, acc[fm][3], 0, 0, 0);
                }
            }
            asm volatile("" ::: "memory");
            __builtin_amdgcn_s_barrier();
            asm volatile("" ::: "memory");
            if (kt + 2 < NKT) {
                STAGE(kt & 1, kt + 2)
                asm volatile("s_waitcnt vmcnt(8)" ::: "memory");
                __builtin_amdgcn_s_barrier();
                asm volatile("" ::: "memory");
            } else if (kt < NKT - 1) {
                asm volatile("s_waitcnt vmcnt(0)" ::: "memory");
                __builtin_amdgcn_s_barrier();
                asm volatile("" ::: "memory");
            }
        }
        #undef STAGE

        // ---- fused LSE epilogue over this 256x256 sim block ----
        float colv[4]; int gcol[4];
        #pragma unroll
        for (int fn = 0; fn < 4; ++fn) {
            const int c = bx * 256 + wcol * 64 + fn * 16 + fr;
            gcol[fn] = c;
            colv[fn] = 5.0f * (slv[c] + cvec[c]) - 1280.0f;   // 5*(slv+cvec-256)
        }
        float* redm = (float*)smem;             // [256][4]
        float* reds = (float*)(smem + 4096);    // [256][4]

        #pragma unroll
        for (int fm = 0; fm < 8; ++fm) {
            #pragma unroll
            for (int q = 0; q < 4; ++q) {
                const int rloc = wrow * 128 + fm * 16 + g * 4 + q;
                const int grow = by * 256 + rloc;
                const float rv = 5.0f * slv[grow];
                const int jpart = grow ^ N_HALF;
                float v[4];
                #pragma unroll
                for (int fn = 0; fn < 4; ++fn) {
                    const float x = 5.0f * acc[fm][fn][q] + colv[fn] - rv;
                    if (gcol[fn] == jpart) pos[grow] = x;      // sim[i, partner(i)]
                    v[fn] = (grow == gcol[fn]) ? -3.0e38f : x;
                }
                float m = fmaxf(fmaxf(v[0], v[1]), fmaxf(v[2], v[3]));
                #pragma unroll
                for (int off = 1; off < 16; off <<= 1) m = fmaxf(m, __shfl_xor(m, off, 64));
                float s = __expf(v[0] - m) + __expf(v[1] - m) + __expf(v[2] - m) + __expf(v[3] - m);
                #pragma unroll
                for (int off = 1; off < 16; off <<= 1) s += __shfl_xor(s, off, 64);
                if (fr == 0) { redm[rloc * 4 + wcol] = m; reds[rloc * 4 + wcol] = s; }
            }
        }
        __syncthreads();
        if (t < 256) {
            float m = redm[t * 4], s = reds[t * 4];
            #pragma unroll
            for (int k = 1; k < 4; ++k) {
                const float mk = redm[t * 4 + k], sk = reds[t * 4 + k];
                const float nm = fmaxf(m, mk);
                s = s * __expf(m - nm) + sk * __expf(mk - nm);
                m = nm;
            }
            pm[(size_t)(by * 256 + t) * NBLK + bx] = m;
            ps[(size_t)(by * 256 + t) * NBLK + bx] = s;
        }
    }
    gbar(cnt, 2u * NBLOCKS);

    // ================= Phase 3: per-row finalize (16 rows/block) =========
    {
        #pragma unroll
        for (int rep = 0; rep < 2; ++rep) {
            const int i = b * 16 + wid * 2 + rep;
            float m = (lane < NBLK) ? pm[(size_t)i * NBLK + lane] : -3.0e38f;
            float s = (lane < NBLK) ? ps[(size_t)i * NBLK + lane] : 0.0f;
            #pragma unroll
            for (int off = 1; off < NBLK; off <<= 1) {
                const float om = __shfl_xor(m, off, 64);
                const float os = __shfl_xor(s, off, 64);
                const float nm = fmaxf(m, om);
                s = s * __expf(m - nm) + os * __expf(om - nm);
                m = nm;
            }
            if (lane == 0) loss[i] = m + logf(s) - pos[i];
        }
    }
    gbar(cnt, 3u * NBLOCKS);

    // ================= Phase 4: mean (block 0 only) ======================
    if (b == 0) {
        float a = 0.0f;
        for (int k = t; k < M_TOT; k += 512) a += loss[k];
        float* sm = (float*)smem;
        sm[t] = a;
        __syncthreads();
        for (int off = 256; off > 0; off >>= 1) {
            if (t < off) sm[t] += sm[t + off];
            __syncthreads();
        }
        if (t == 0) out[0] = sm[0] * (1.0f / (float)M_TOT);
    }
}

// ---------------------------------------------------------------------------
extern "C" void kernel_launch(void* const* d_in, const int* in_sizes, int n_in,
                              void* d_out, int out_size, void* d_ws, size_t ws_size,
                              hipStream_t stream) {
    const float* loc1   = (const float*)d_in[0];
    const float* scale1 = (const float*)d_in[1];
    const float* loc2   = (const float*)d_in[2];
    const float* scale2 = (const float*)d_in[3];
    float* out = (float*)d_out;

    char* ws = (char*)d_ws;
    unsigned short* Ab = (unsigned short*)ws;                              // 4 MB
    unsigned short* Bb = (unsigned short*)(ws + (size_t)4 * 1024 * 1024);  // 4 MB
    float* slv  = (float*)(ws + (size_t)8 * 1024 * 1024);                  // 16 KB
    float* cvec = slv + M_TOT;
    float* pm   = cvec + M_TOT;                                            // 256 KB
    float* ps   = pm + (size_t)M_TOT * NBLK;                               // 256 KB
    float* pos  = ps + (size_t)M_TOT * NBLK;                               // 16 KB
    float* loss = pos + M_TOT;                                             // 16 KB
    unsigned* cnt = (unsigned*)(ws + (size_t)12 * 1024 * 1024);            // 64 B

    hipMemsetAsync(cnt, 0, 64, stream);
    hipLaunchKernelGGL(mega_kernel, dim3(256), dim3(512), 131072, stream,
                       loc1, scale1, loc2, scale2, Ab, Bb, slv, cvec,
                       pm, ps, pos, loss, out, cnt);
}

// Round 7
// 51.196 us; speedup vs baseline: 6.5052x; 6.5052x over previous
//
#include <hip/hip_runtime.h>
#include <hip/hip_bf16.h>
#include <math.h>

#define N_HALF 2048
#define M_TOT  4096
#define D_DIM  256
#define K2     512
#define NBLK   16            // M_TOT / 256 column blocks
#define NKT    8             // K2 / 64 k-tiles
#define TILE_BYTES 32768     // 256 rows * 64 k * 2 B

typedef __attribute__((ext_vector_type(8))) short bf16x8;
typedef __attribute__((ext_vector_type(4))) float f32x4;

static __device__ __forceinline__ unsigned short f2bf(float x) {
    union { __hip_bfloat16 h; unsigned short u; } cv;
    cv.h = __float2bfloat16(x);
    return cv.u;
}

static __device__ __forceinline__ void gll16(const void* g, void* l) {
    __builtin_amdgcn_global_load_lds(
        (const __attribute__((address_space(1))) unsigned int*)g,
        (__attribute__((address_space(3))) unsigned int*)l, 16, 0, 0);
}

// ---------------------------------------------------------------------------
// Kernel 1: build bf16 GEMM operands (pre-swizzled, tile-major) + row scalars.
//   A[i] = [mu^2+var , -2*mu],  B[j] = [1/var , mu/var]   (each K=512)
//   Tiles of 256 rows x 64 k bf16 (32 KB); row r's 8 16B-slots XOR-swizzled
//   slot' = slot ^ (r&7) so linear global_load_lds yields swizzled LDS image.
// ---------------------------------------------------------------------------
__global__ __launch_bounds__(256) void prep_kernel(
        const float* __restrict__ loc1, const float* __restrict__ scale1,
        const float* __restrict__ loc2, const float* __restrict__ scale2,
        unsigned short* __restrict__ Ab, unsigned short* __restrict__ Bb,
        float* __restrict__ slv, float* __restrict__ cvec) {
    const int t = threadIdx.x, w = t >> 6, lane = t & 63;
    const int i = blockIdx.x * 4 + w;
    const float* mup  = (i < N_HALF) ? loc1 + (size_t)i * D_DIM   : loc2 + (size_t)(i - N_HALF) * D_DIM;
    const float* vap  = (i < N_HALF) ? scale1 + (size_t)i * D_DIM : scale2 + (size_t)(i - N_HALF) * D_DIM;
    const float4 mu = *(const float4*)(mup + lane * 4);
    const float4 va = *(const float4*)(vap + lane * 4);
    const float4 iv = {1.0f / va.x, 1.0f / va.y, 1.0f / va.z, 1.0f / va.w};

    float lacc = __logf(va.x * va.y * va.z * va.w);
    float cacc = mu.x * mu.x * iv.x + mu.y * mu.y * iv.y
               + mu.z * mu.z * iv.z + mu.w * mu.w * iv.w;
    #pragma unroll
    for (int off = 1; off < 64; off <<= 1) {
        lacc += __shfl_xor(lacc, off, 64);
        cacc += __shfl_xor(cacc, off, 64);
    }
    if (lane == 0) { slv[i] = lacc; cvec[i] = cacc; }

    const int by = i >> 8, r = i & 255;
    const int rsw = r & 7;
    char* const abase = (char*)Ab + (size_t)by * (NKT * TILE_BYTES) + r * 128;
    char* const bbase = (char*)Bb + (size_t)by * (NKT * TILE_BYTES) + r * 128;
    #define ST4(base, k, v0, v1, v2, v3)                                            \
        {   const int kk = (k);                                                     \
            const int kb = kk >> 6, sl = ((kk >> 3) & 7) ^ rsw, hf = (kk >> 2) & 1; \
            ushort4 pk = {f2bf(v0), f2bf(v1), f2bf(v2), f2bf(v3)};                  \
            *(ushort4*)((base) + (size_t)kb * TILE_BYTES + sl * 16 + hf * 8) = pk; }
    ST4(abase, lane * 4,          mu.x * mu.x + va.x, mu.y * mu.y + va.y,
                                  mu.z * mu.z + va.z, mu.w * mu.w + va.w)
    ST4(abase, 256 + lane * 4,    -2.0f * mu.x, -2.0f * mu.y, -2.0f * mu.z, -2.0f * mu.w)
    ST4(bbase, lane * 4,          iv.x, iv.y, iv.z, iv.w)
    ST4(bbase, 256 + lane * 4,    mu.x * iv.x, mu.y * iv.y, mu.z * iv.z, mu.w * iv.w)
    #undef ST4
}

// ---------------------------------------------------------------------------
// Kernel 2: bf16 MFMA GEMM, 256x256 tile, 8 waves (2Mx4N), BK=64,
// double-buffered LDS (128 KB), counted-vmcnt 2-K-tile pipeline.
// Fused LSE epilogue -> (m,s) per (row,colblock) + pos[i] = sim[i, i^2048].
// ---------------------------------------------------------------------------
__global__ __launch_bounds__(512, 2) void gemm_lse_kernel(
        const unsigned short* __restrict__ Ab, const unsigned short* __restrict__ Bb,
        const float* __restrict__ slv, const float* __restrict__ cvec,
        float* __restrict__ pm, float* __restrict__ ps,
        float* __restrict__ pos) {
    extern __shared__ __align__(16) char smem[];   // 131072 B
    const int t = threadIdx.x;
    const int lane = t & 63, wid = t >> 6;
    const int bx = blockIdx.x, by = blockIdx.y;
    const int wrow = wid >> 2, wcol = wid & 3;     // 2 x 4 wave grid
    const int fr = lane & 15, g = lane >> 4;
    const int t16 = t * 16;

    int a_off[8][2], b_off[4][2];
    #pragma unroll
    for (int fm = 0; fm < 8; ++fm) {
        const int row = wrow * 128 + fm * 16 + fr;
        #pragma unroll
        for (int ks = 0; ks < 2; ++ks)
            a_off[fm][ks] = row * 128 + ((((ks * 4 + g) ^ (row & 7))) << 4);
    }
    #pragma unroll
    for (int fn = 0; fn < 4; ++fn) {
        const int row = wcol * 64 + fn * 16 + fr;
        #pragma unroll
        for (int ks = 0; ks < 2; ++ks)
            b_off[fn][ks] = 32768 + row * 128 + ((((ks * 4 + g) ^ (row & 7))) << 4);
    }

    f32x4 acc[8][4];
    #pragma unroll
    for (int i = 0; i < 8; ++i)
        #pragma unroll
        for (int j = 0; j < 4; ++j) acc[i][j] = (f32x4){0.f, 0.f, 0.f, 0.f};

    const char* gA = (const char*)Ab + (size_t)by * (NKT * TILE_BYTES);
    const char* gB = (const char*)Bb + (size_t)bx * (NKT * TILE_BYTES);

    #define STAGE(buf, kt)                                                       \
        {   const char* _tA = gA + (size_t)(kt) * TILE_BYTES;                    \
            const char* _tB = gB + (size_t)(kt) * TILE_BYTES;                    \
            char* _dA = smem + (buf) * 65536;                                    \
            char* _dB = _dA + 32768;                                             \
            gll16(_tA + t16,         _dA + t16);                                 \
            gll16(_tA + 8192 + t16,  _dA + 8192 + t16);                          \
            gll16(_tA + 16384 + t16, _dA + 16384 + t16);                         \
            gll16(_tA + 24576 + t16, _dA + 24576 + t16);                         \
            gll16(_tB + t16,         _dB + t16);                                 \
            gll16(_tB + 8192 + t16,  _dB + 8192 + t16);                          \
            gll16(_tB + 16384 + t16, _dB + 16384 + t16);                         \
            gll16(_tB + 24576 + t16, _dB + 24576 + t16); }

    STAGE(0, 0)
    STAGE(1, 1)
    asm volatile("s_waitcnt vmcnt(8)" ::: "memory");   // tile 0 resident
    __builtin_amdgcn_s_barrier();
    asm volatile("" ::: "memory");

    for (int kt = 0; kt < NKT; ++kt) {
        const char* bT = smem + (kt & 1) * 65536;
        #pragma unroll
        for (int ks = 0; ks < 2; ++ks) {
            bf16x8 b0 = *(const bf16x8*)(bT + b_off[0][ks]);
            bf16x8 b1 = *(const bf16x8*)(bT + b_off[1][ks]);
            bf16x8 b2 = *(const bf16x8*)(bT + b_off[2][ks]);
            bf16x8 b3 = *(const bf16x8*)(bT + b_off[3][ks]);
            #pragma unroll
            for (int fm = 0; fm < 8; ++fm) {
                const bf16x8 af = *(const bf16x8*)(bT + a_off[fm][ks]);
                acc[fm][0] = __builtin_amdgcn_mfma_f32_16x16x32_bf16(af, b0, acc[fm][0], 0, 0, 0);
                acc[fm][1] = __builtin_amdgcn_mfma_f32_16x16x32_bf16(af, b1, acc[fm][1], 0, 0, 0);
                acc[fm][2] = __builtin_amdgcn_mfma_f32_16x16x32_bf16(af, b2, acc[fm][2], 0, 0, 0);
                acc[fm][3] = __builtin_amdgcn_mfma_f32_16x16x32_bf16(af, b3, acc[fm][3], 0, 0, 0);
            }
        }
        asm volatile("" ::: "memory");
        __builtin_amdgcn_s_barrier();
        asm volatile("" ::: "memory");
        if (kt + 2 < NKT) {
            STAGE(kt & 1, kt + 2)
            asm volatile("s_waitcnt vmcnt(8)" ::: "memory");
            __builtin_amdgcn_s_barrier();
            asm volatile("" ::: "memory");
        } else if (kt < NKT - 1) {
            asm volatile("s_waitcnt vmcnt(0)" ::: "memory");
            __builtin_amdgcn_s_barrier();
            asm volatile("" ::: "memory");
        }
    }
    #undef STAGE

    // ---- fused LSE epilogue over this 256x256 sim block ----
    float colv[4]; int gcol[4];
    #pragma unroll
    for (int fn = 0; fn < 4; ++fn) {
        const int c = bx * 256 + wcol * 64 + fn * 16 + fr;
        gcol[fn] = c;
        colv[fn] = 5.0f * (slv[c] + cvec[c]) - 1280.0f;   // 5*(slv+cvec-256)
    }
    float* redm = (float*)smem;             // [256][4]
    float* reds = (float*)(smem + 4096);    // [256][4]

    #pragma unroll
    for (int fm = 0; fm < 8; ++fm) {
        #pragma unroll
        for (int q = 0; q < 4; ++q) {
            const int rloc = wrow * 128 + fm * 16 + g * 4 + q;
            const int grow = by * 256 + rloc;
            const float rv = 5.0f * slv[grow];
            const int jpart = grow ^ N_HALF;
            float v[4];
            #pragma unroll
            for (int fn = 0; fn < 4; ++fn) {
                const float x = 5.0f * acc[fm][fn][q] + colv[fn] - rv;
                if (gcol[fn] == jpart) pos[grow] = x;      // sim[i, partner(i)]
                v[fn] = (grow == gcol[fn]) ? -3.0e38f : x;
            }
            float m = fmaxf(fmaxf(v[0], v[1]), fmaxf(v[2], v[3]));
            #pragma unroll
            for (int off = 1; off < 16; off <<= 1) m = fmaxf(m, __shfl_xor(m, off, 64));
            float s = __expf(v[0] - m) + __expf(v[1] - m) + __expf(v[2] - m) + __expf(v[3] - m);
            #pragma unroll
            for (int off = 1; off < 16; off <<= 1) s += __shfl_xor(s, off, 64);
            if (fr == 0) { redm[rloc * 4 + wcol] = m; reds[rloc * 4 + wcol] = s; }
        }
    }
    __syncthreads();
    if (t < 256) {
        float m = redm[t * 4], s = reds[t * 4];
        #pragma unroll
        for (int k = 1; k < 4; ++k) {
            const float mk = redm[t * 4 + k], sk = reds[t * 4 + k];
            const float nm = fmaxf(m, mk);
            s = s * __expf(m - nm) + sk * __expf(mk - nm);
            m = nm;
        }
        pm[(size_t)(by * 256 + t) * NBLK + bx] = m;
        ps[(size_t)(by * 256 + t) * NBLK + bx] = s;
    }
}

// ---------------------------------------------------------------------------
// Kernel 3: fused finalize + mean. Single block, 1024 threads, 4 rows each:
// combine 16 (m,s) partials two-pass -> lse; loss = lse - pos; block-mean.
// ---------------------------------------------------------------------------
__global__ __launch_bounds__(1024) void finmean_kernel(
        const float* __restrict__ pm, const float* __restrict__ ps,
        const float* __restrict__ pos, float* __restrict__ out) {
    __shared__ float sm[1024];
    const int t = threadIdx.x;
    float acc = 0.0f;
    for (int i = t; i < M_TOT; i += 1024) {
        float mk[NBLK];
        float m = -3.0e38f;
        #pragma unroll
        for (int k = 0; k < NBLK; ++k) {
            mk[k] = pm[(size_t)i * NBLK + k];
            m = fmaxf(m, mk[k]);
        }
        float s = 0.0f;
        #pragma unroll
        for (int k = 0; k < NBLK; ++k)
            s += ps[(size_t)i * NBLK + k] * __expf(mk[k] - m);
        acc += m + logf(s) - pos[i];
    }
    sm[t] = acc;
    __syncthreads();
    for (int off = 512; off > 0; off >>= 1) {
        if (t < off) sm[t] += sm[t + off];
        __syncthreads();
    }
    if (t == 0) out[0] = sm[0] * (1.0f / (float)M_TOT);
}

// ---------------------------------------------------------------------------
extern "C" void kernel_launch(void* const* d_in, const int* in_sizes, int n_in,
                              void* d_out, int out_size, void* d_ws, size_t ws_size,
                              hipStream_t stream) {
    const float* loc1   = (const float*)d_in[0];
    const float* scale1 = (const float*)d_in[1];
    const float* loc2   = (const float*)d_in[2];
    const float* scale2 = (const float*)d_in[3];
    float* out = (float*)d_out;

    char* ws = (char*)d_ws;
    unsigned short* Ab = (unsigned short*)ws;                              // 4 MB
    unsigned short* Bb = (unsigned short*)(ws + (size_t)4 * 1024 * 1024);  // 4 MB
    float* slv  = (float*)(ws + (size_t)8 * 1024 * 1024);                  // 16 KB
    float* cvec = slv + M_TOT;
    float* pm   = cvec + M_TOT;                                            // 256 KB
    float* ps   = pm + (size_t)M_TOT * NBLK;                               // 256 KB
    float* pos  = ps + (size_t)M_TOT * NBLK;                               // 16 KB

    hipLaunchKernelGGL(prep_kernel, dim3(M_TOT / 4), dim3(256), 0, stream,
                       loc1, scale1, loc2, scale2, Ab, Bb, slv, cvec);
    hipLaunchKernelGGL(gemm_lse_kernel, dim3(NBLK, NBLK), dim3(512), 131072, stream,
                       Ab, Bb, slv, cvec, pm, ps, pos);
    hipLaunchKernelGGL(finmean_kernel, dim3(1), dim3(1024), 0, stream,
                       pm, ps, pos, out);
}